// Round 1
// baseline (309.000 us; speedup 1.0000x reference)
//
#include <hip/hip_runtime.h>
#include <hip/hip_bf16.h>

// Problem constants (from reference)
#define NB 2
#define NC 1024
#define NT 1536
#define NH 16
#define ND 64
#define NBT 3072   // NB*NT
#define ATTN_SCALE 0.125f
#define LN_EPS 1e-5f

typedef __attribute__((ext_vector_type(8))) __bf16 bf16x8;
typedef __attribute__((ext_vector_type(4))) float f32x4;

__device__ __forceinline__ unsigned short f2bf(float f) {
    unsigned u = __float_as_uint(f);
    u += 0x7fffu + ((u >> 16) & 1u);   // round-to-nearest-even
    return (unsigned short)(u >> 16);
}
__device__ __forceinline__ float bf2f(unsigned short s) {
    return __uint_as_float(((unsigned)s) << 16);
}
__device__ __forceinline__ f32x4 mfma16(bf16x8 a, bf16x8 b, f32x4 c) {
    return __builtin_amdgcn_mfma_f32_16x16x32_bf16(a, b, c, 0, 0, 0);
}
__device__ __forceinline__ bf16x8 ldbf8(const unsigned short* p) {
    return *reinterpret_cast<const bf16x8*>(p);
}

// ---------------------------------------------------------------------------
// Convert f32 1024x1024 weights -> bf16 (so GEMMs can read bf16 fragments)
// grid (1024, 4), block 256; each thread converts 4 elements.
__global__ __launch_bounds__(256) void wcvt_kernel(
    const float* __restrict__ w0, const float* __restrict__ w1,
    const float* __restrict__ w2, const float* __restrict__ w3,
    unsigned short* __restrict__ o0, unsigned short* __restrict__ o1,
    unsigned short* __restrict__ o2, unsigned short* __restrict__ o3)
{
    const float* src; unsigned short* dst;
    switch (blockIdx.y) {
        case 0: src = w0; dst = o0; break;
        case 1: src = w1; dst = o1; break;
        case 2: src = w2; dst = o2; break;
        default: src = w3; dst = o3; break;
    }
    int i = (blockIdx.x * 256 + threadIdx.x) * 4;
    float4 v = *reinterpret_cast<const float4*>(src + i);
    ushort4 r;
    r.x = f2bf(v.x); r.y = f2bf(v.y); r.z = f2bf(v.z); r.w = f2bf(v.w);
    *reinterpret_cast<ushort4*>(dst + i) = r;
}

// ---------------------------------------------------------------------------
// Depthwise conv3 (pad 1) -> mask -> channel LayerNorm -> bf16, transposed
// output layout [bt][c].  grid (NT/16, NB, 3), block 256.
__global__ __launch_bounds__(256) void convln_kernel(
    const float* __restrict__ x, const float* __restrict__ y, const float* __restrict__ z,
    const float* __restrict__ qw, const float* __restrict__ kw, const float* __restrict__ vw,
    const float* __restrict__ qg, const float* __restrict__ qb,
    const float* __restrict__ kgm, const float* __restrict__ kbt,
    const float* __restrict__ vg, const float* __restrict__ vb,
    const int* __restrict__ mask,
    unsigned short* __restrict__ xn, unsigned short* __restrict__ yn,
    unsigned short* __restrict__ zn)
{
    __shared__ __align__(16) unsigned short tile[16 * 1032]; // conv result, bf16, stride-padded
    __shared__ float psum[16][17], psq[16][17];
    __shared__ float smu[16], srs[16];

    const float* src; const float* cw; const float* g; const float* be;
    unsigned short* dst;
    if (blockIdx.z == 0)      { src = x; cw = qw; g = qg;  be = qb;  dst = xn; }
    else if (blockIdx.z == 1) { src = y; cw = kw; g = kgm; be = kbt; dst = yn; }
    else                      { src = z; cw = vw; g = vg;  be = vb;  dst = zn; }

    int b  = blockIdx.y;
    int t0 = blockIdx.x * 16;
    int tid = threadIdx.x;
    int tt = tid & 15, cc = tid >> 4;
    int t = t0 + tt;
    float mval = (mask[b * NT + t] != 0) ? 1.f : 0.f;

    const float* sb = src + (size_t)b * NC * NT;
    float sum = 0.f, ssq = 0.f;
    for (int c0 = 0; c0 < NC; c0 += 16) {
        int c = c0 + cc;
        const float* xp = sb + (size_t)c * NT;
        float v0 = xp[t];
        float vm = __shfl_up(v0, 1, 16);
        float vp = __shfl_down(v0, 1, 16);
        if (tt == 0)  vm = (t > 0)      ? xp[t - 1] : 0.f;
        if (tt == 15) vp = (t + 1 < NT) ? xp[t + 1] : 0.f;
        float w0 = cw[c * 3], w1 = cw[c * 3 + 1], w2 = cw[c * 3 + 2];
        float conv = (w0 * vm + w1 * v0 + w2 * vp) * mval;
        tile[tt * 1032 + c] = f2bf(conv);
        sum += conv; ssq += conv * conv;
    }
    psum[cc][tt] = sum; psq[cc][tt] = ssq;
    __syncthreads();
    if (tid < 16) {
        float s = 0.f, q2 = 0.f;
        for (int j = 0; j < 16; ++j) { s += psum[j][tid]; q2 += psq[j][tid]; }
        float mu = s * (1.f / 1024.f);
        float var = q2 * (1.f / 1024.f) - mu * mu;
        smu[tid] = mu;
        srs[tid] = rsqrtf(var + LN_EPS);
    }
    __syncthreads();

    int c4 = tid * 4;
    float g0 = g[c4], g1 = g[c4 + 1], g2 = g[c4 + 2], g3 = g[c4 + 3];
    float e0 = be[c4], e1 = be[c4 + 1], e2 = be[c4 + 2], e3 = be[c4 + 3];
    for (int r = 0; r < 16; ++r) {
        ushort4 tv = *reinterpret_cast<const ushort4*>(&tile[r * 1032 + c4]);
        float mu = smu[r], rs = srs[r];
        ushort4 o;
        o.x = f2bf((bf2f(tv.x) - mu) * rs * g0 + e0);
        o.y = f2bf((bf2f(tv.y) - mu) * rs * g1 + e1);
        o.z = f2bf((bf2f(tv.z) - mu) * rs * g2 + e2);
        o.w = f2bf((bf2f(tv.w) - mu) * rs * g3 + e3);
        *reinterpret_cast<ushort4*>(dst + (size_t)(b * NT + t0 + r) * NC + c4) = o;
    }
}

// ---------------------------------------------------------------------------
// q/k/v projections: OUT[n][o] = sum_c W[o][c] * X[n][c] + bias[o]  (bf16 out)
// v variant writes transposed vt[o][n] for the attention PV step.
// grid (24, 8, 3), block 256 (4 waves, 2x2, 64x64 per wave, K-step 32).
__global__ __launch_bounds__(256) void gemm_qkv_kernel(
    const unsigned short* __restrict__ wqb, const unsigned short* __restrict__ wkb,
    const unsigned short* __restrict__ wvb,
    const unsigned short* __restrict__ xn, const unsigned short* __restrict__ yn,
    const unsigned short* __restrict__ zn,
    const float* __restrict__ bq, const float* __restrict__ bk, const float* __restrict__ bv,
    unsigned short* __restrict__ qo, unsigned short* __restrict__ ko,
    unsigned short* __restrict__ vt)
{
    int which = blockIdx.z;
    const unsigned short* W = (which == 0) ? wqb : (which == 1) ? wkb : wvb;
    const unsigned short* X = (which == 0) ? xn : (which == 1) ? yn : zn;
    const float* bias = (which == 0) ? bq : (which == 1) ? bk : bv;

    int lane = threadIdx.x & 63, w = threadIdx.x >> 6;
    int wm = w >> 1, wn = w & 1;
    int ob = blockIdx.y * 128 + wm * 64;  // M = out-channel
    int nb = blockIdx.x * 128 + wn * 64;  // N = bt
    int r0 = lane & 15, kg = lane >> 4;

    f32x4 acc[4][4];
    #pragma unroll
    for (int i = 0; i < 4; ++i)
        #pragma unroll
        for (int j = 0; j < 4; ++j) acc[i][j] = (f32x4){0.f, 0.f, 0.f, 0.f};

    const unsigned short* Ap = W + (size_t)(ob + r0) * NC + kg * 8;
    const unsigned short* Bp = X + (size_t)(nb + r0) * NC + kg * 8;

    for (int k0 = 0; k0 < NC; k0 += 32) {
        bf16x8 a[4], bb[4];
        #pragma unroll
        for (int i = 0; i < 4; ++i) a[i]  = ldbf8(Ap + (size_t)i * 16 * NC + k0);
        #pragma unroll
        for (int i = 0; i < 4; ++i) bb[i] = ldbf8(Bp + (size_t)i * 16 * NC + k0);
        #pragma unroll
        for (int mf = 0; mf < 4; ++mf)
            #pragma unroll
            for (int nf = 0; nf < 4; ++nf)
                acc[mf][nf] = mfma16(a[mf], bb[nf], acc[mf][nf]);
    }

    if (which < 2) {
        unsigned short* OUT = (which == 0) ? qo : ko;
        #pragma unroll
        for (int mf = 0; mf < 4; ++mf) {
            int o0 = ob + mf * 16 + kg * 4;        // D-layout row base
            float4 bz = *reinterpret_cast<const float4*>(bias + o0);
            #pragma unroll
            for (int nf = 0; nf < 4; ++nf) {
                int n = nb + nf * 16 + r0;         // D-layout col
                ushort4 st;
                st.x = f2bf(acc[mf][nf][0] + bz.x);
                st.y = f2bf(acc[mf][nf][1] + bz.y);
                st.z = f2bf(acc[mf][nf][2] + bz.z);
                st.w = f2bf(acc[mf][nf][3] + bz.w);
                *reinterpret_cast<ushort4*>(OUT + (size_t)n * NC + o0) = st;
            }
        }
    } else {
        #pragma unroll
        for (int mf = 0; mf < 4; ++mf) {
            int o0 = ob + mf * 16 + kg * 4;
            #pragma unroll
            for (int nf = 0; nf < 4; ++nf) {
                int n = nb + nf * 16 + r0;
                #pragma unroll
                for (int r = 0; r < 4; ++r)
                    vt[(size_t)(o0 + r) * NBT + n] = f2bf(acc[mf][nf][r] + bias[o0 + r]);
            }
        }
    }
}

// ---------------------------------------------------------------------------
// Flash attention. grid (NT/64, NB*NH), block 256 = 4 waves x 16 q-rows.
// q,k: [bt][c] bf16; vt: [c][bt] bf16; output oatt: [bt][c] bf16.
__global__ __launch_bounds__(256) void attn_kernel(
    const unsigned short* __restrict__ q, const unsigned short* __restrict__ kk,
    const unsigned short* __restrict__ vt, const int* __restrict__ mask,
    unsigned short* __restrict__ oatt)
{
    __shared__ __align__(16) unsigned short plds[4][16 * 72]; // per-wave P bounce

    int lane = threadIdx.x & 63;
    int w = threadIdx.x >> 6;
    int b = blockIdx.y >> 4, h = blockIdx.y & 15;
    int q0 = blockIdx.x * 64 + w * 16;
    int r0 = lane & 15, kg = lane >> 4;

    const unsigned short* qp = q + (size_t)(b * NT + q0 + r0) * NC + h * ND + kg * 8;
    bf16x8 qa0 = ldbf8(qp);
    bf16x8 qa1 = ldbf8(qp + 32);

    f32x4 oacc[4];
    #pragma unroll
    for (int i = 0; i < 4; ++i) oacc[i] = (f32x4){0.f, 0.f, 0.f, 0.f};
    float m_r[4], l_r[4];
    #pragma unroll
    for (int r = 0; r < 4; ++r) { m_r[r] = -1e30f; l_r[r] = 0.f; }

    const int* mrow = mask + b * NT;
    const unsigned short* kbase = kk + ((size_t)(b * NT)) * NC + h * ND;
    const unsigned short* vbase = vt + (size_t)(h * ND) * NBT + b * NT;
    unsigned short* pl = &plds[w][0];

    for (int kb = 0; kb < NT; kb += 64) {
        if (!__any(mrow[kb + lane] != 0)) break;  // prefix mask -> exact early stop

        // S = Q K^T  (per wave: 16 q-rows x 64 keys)
        f32x4 s[4];
        #pragma unroll
        for (int nf = 0; nf < 4; ++nf) {
            const unsigned short* kp = kbase + (size_t)(kb + nf * 16 + r0) * NC + kg * 8;
            f32x4 zz = (f32x4){0.f, 0.f, 0.f, 0.f};
            zz = mfma16(qa0, ldbf8(kp), zz);
            zz = mfma16(qa1, ldbf8(kp + 32), zz);
            s[nf] = zz;
        }
        // scale + key mask
        #pragma unroll
        for (int nf = 0; nf < 4; ++nf) {
            float addm = (mrow[kb + nf * 16 + r0] != 0) ? 0.f : -1e30f;
            #pragma unroll
            for (int r = 0; r < 4; ++r) s[nf][r] = s[nf][r] * ATTN_SCALE + addm;
        }
        // online softmax (rows live on 16-lane groups)
        float rm[4];
        #pragma unroll
        for (int r = 0; r < 4; ++r)
            rm[r] = fmaxf(fmaxf(s[0][r], s[1][r]), fmaxf(s[2][r], s[3][r]));
        #pragma unroll
        for (int off = 1; off < 16; off <<= 1)
            #pragma unroll
            for (int r = 0; r < 4; ++r)
                rm[r] = fmaxf(rm[r], __shfl_xor(rm[r], off, 64));
        float resc[4], rs[4];
        #pragma unroll
        for (int r = 0; r < 4; ++r) {
            float mn = fmaxf(m_r[r], rm[r]);
            resc[r] = __expf(m_r[r] - mn);
            m_r[r] = mn;
            rs[r] = 0.f;
        }
        unsigned short pb16[4][4];
        #pragma unroll
        for (int nf = 0; nf < 4; ++nf)
            #pragma unroll
            for (int r = 0; r < 4; ++r) {
                float p = __expf(s[nf][r] - m_r[r]);
                rs[r] += p;
                pb16[nf][r] = f2bf(p);
            }
        #pragma unroll
        for (int off = 1; off < 16; off <<= 1)
            #pragma unroll
            for (int r = 0; r < 4; ++r)
                rs[r] += __shfl_xor(rs[r], off, 64);
        #pragma unroll
        for (int r = 0; r < 4; ++r) l_r[r] = l_r[r] * resc[r] + rs[r];
        #pragma unroll
        for (int df = 0; df < 4; ++df)
            #pragma unroll
            for (int r = 0; r < 4; ++r) oacc[df][r] *= resc[r];

        // bounce P through LDS (D-layout -> A-fragment layout)
        #pragma unroll
        for (int nf = 0; nf < 4; ++nf)
            #pragma unroll
            for (int r = 0; r < 4; ++r)
                pl[(kg * 4 + r) * 72 + nf * 16 + r0] = pb16[nf][r];
        bf16x8 pa0 = ldbf8(pl + r0 * 72 + kg * 8);
        bf16x8 pa1 = ldbf8(pl + r0 * 72 + 32 + kg * 8);

        // O += P V   (V fragments contiguous thanks to vt transpose)
        #pragma unroll
        for (int df = 0; df < 4; ++df) {
            const unsigned short* vp = vbase + (size_t)(df * 16 + r0) * NBT + kb + kg * 8;
            oacc[df] = mfma16(pa0, ldbf8(vp), oacc[df]);
            oacc[df] = mfma16(pa1, ldbf8(vp + 32), oacc[df]);
        }
    }

    float inv[4];
    #pragma unroll
    for (int r = 0; r < 4; ++r) inv[r] = 1.f / l_r[r];
    unsigned short* ob = oatt + (size_t)(b * NT + q0 + kg * 4) * NC + h * ND;
    #pragma unroll
    for (int df = 0; df < 4; ++df)
        #pragma unroll
        for (int r = 0; r < 4; ++r)
            ob[(size_t)r * NC + df * 16 + r0] = f2bf(oacc[df][r] * inv[r]);
}

// ---------------------------------------------------------------------------
// Output projection, role-swapped (M = bt) so stores run contiguous along T.
// out[b][o][t] = (sum_c oatt[bt][c]*wp[o][c] + bp[o]) * mask[bt]
// grid (24, 8), block 256.
__global__ __launch_bounds__(256) void gemm_out_kernel(
    const unsigned short* __restrict__ oatt, const unsigned short* __restrict__ wpb,
    const float* __restrict__ bp, const int* __restrict__ mask,
    float* __restrict__ out)
{
    int lane = threadIdx.x & 63, w = threadIdx.x >> 6;
    int wm = w >> 1, wn = w & 1;
    int mb  = blockIdx.x * 128 + wm * 64;  // M = bt
    int obb = blockIdx.y * 128 + wn * 64;  // N = out-channel
    int r0 = lane & 15, kg = lane >> 4;

    f32x4 acc[4][4];
    #pragma unroll
    for (int i = 0; i < 4; ++i)
        #pragma unroll
        for (int j = 0; j < 4; ++j) acc[i][j] = (f32x4){0.f, 0.f, 0.f, 0.f};

    const unsigned short* Ap = oatt + (size_t)(mb + r0) * NC + kg * 8;
    const unsigned short* Bp = wpb + (size_t)(obb + r0) * NC + kg * 8;

    for (int k0 = 0; k0 < NC; k0 += 32) {
        bf16x8 a[4], bb[4];
        #pragma unroll
        for (int i = 0; i < 4; ++i) a[i]  = ldbf8(Ap + (size_t)i * 16 * NC + k0);
        #pragma unroll
        for (int i = 0; i < 4; ++i) bb[i] = ldbf8(Bp + (size_t)i * 16 * NC + k0);
        #pragma unroll
        for (int mf = 0; mf < 4; ++mf)
            #pragma unroll
            for (int nf = 0; nf < 4; ++nf)
                acc[mf][nf] = mfma16(a[mf], bb[nf], acc[mf][nf]);
    }

    int b_ = (int)(blockIdx.x >= 12);   // bt tiles never straddle batch boundary
    size_t obase = (size_t)b_ * NC * NT;
    #pragma unroll
    for (int mf = 0; mf < 4; ++mf) {
        int bt0 = mb + mf * 16 + kg * 4;
        int4 mv = *reinterpret_cast<const int4*>(mask + bt0);
        float m0 = mv.x ? 1.f : 0.f;
        float m1 = mv.y ? 1.f : 0.f;
        float m2 = mv.z ? 1.f : 0.f;
        float m3 = mv.w ? 1.f : 0.f;
        int t0 = bt0 - b_ * NT;
        #pragma unroll
        for (int nf = 0; nf < 4; ++nf) {
            int o = obb + nf * 16 + r0;
            float bz = bp[o];
            f32x4 vv;
            vv[0] = (acc[mf][nf][0] + bz) * m0;
            vv[1] = (acc[mf][nf][1] + bz) * m1;
            vv[2] = (acc[mf][nf][2] + bz) * m2;
            vv[3] = (acc[mf][nf][3] + bz) * m3;
            *reinterpret_cast<f32x4*>(out + obase + (size_t)o * NT + t0) = vv;
        }
    }
}

// ---------------------------------------------------------------------------
__global__ __launch_bounds__(256) void maskout_kernel(const int* __restrict__ mask,
                                                      float* __restrict__ out)
{
    int i = blockIdx.x * 256 + threadIdx.x;
    if (i < NBT) out[(size_t)NB * NC * NT + i] = (mask[i] != 0) ? 1.f : 0.f;
}

// ---------------------------------------------------------------------------
extern "C" void kernel_launch(void* const* d_in, const int* in_sizes, int n_in,
                              void* d_out, int out_size, void* d_ws, size_t ws_size,
                              hipStream_t stream)
{
    const float* x    = (const float*)d_in[0];
    const float* y    = (const float*)d_in[1];
    const float* z    = (const float*)d_in[2];
    const int*   mask = (const int*)d_in[3];
    const float* qw   = (const float*)d_in[4];
    const float* kw   = (const float*)d_in[5];
    const float* vw   = (const float*)d_in[6];
    const float* qg   = (const float*)d_in[7];
    const float* qb   = (const float*)d_in[8];
    const float* kgm  = (const float*)d_in[9];
    const float* kbt  = (const float*)d_in[10];
    const float* vg   = (const float*)d_in[11];
    const float* vb   = (const float*)d_in[12];
    const float* wq   = (const float*)d_in[13];
    const float* bq   = (const float*)d_in[14];
    const float* wk   = (const float*)d_in[15];
    const float* bk   = (const float*)d_in[16];
    const float* wv   = (const float*)d_in[17];
    const float* bv   = (const float*)d_in[18];
    const float* wp   = (const float*)d_in[19];
    const float* bp   = (const float*)d_in[20];

    unsigned short* xn  = (unsigned short*)d_ws;
    unsigned short* yn  = xn + (size_t)NBT * NC;
    unsigned short* zn  = yn + (size_t)NBT * NC;
    unsigned short* qo  = zn + (size_t)NBT * NC;
    unsigned short* ko  = qo + (size_t)NBT * NC;
    unsigned short* vt  = ko + (size_t)NBT * NC;
    unsigned short* wqb = vt + (size_t)NBT * NC;
    unsigned short* wkb = wqb + (size_t)NC * NC;
    unsigned short* wvb = wkb + (size_t)NC * NC;
    unsigned short* wpb = wvb + (size_t)NC * NC;
    unsigned short* oatt = xn;  // xn dead after gemm_qkv; reuse for attention out

    float* out = (float*)d_out;

    wcvt_kernel<<<dim3(1024, 4), 256, 0, stream>>>(wq, wk, wv, wp, wqb, wkb, wvb, wpb);
    convln_kernel<<<dim3(NT / 16, NB, 3), 256, 0, stream>>>(
        x, y, z, qw, kw, vw, qg, qb, kgm, kbt, vg, vb, mask, xn, yn, zn);
    gemm_qkv_kernel<<<dim3(NBT / 128, NC / 128, 3), 256, 0, stream>>>(
        wqb, wkb, wvb, xn, yn, zn, bq, bk, bv, qo, ko, vt);
    attn_kernel<<<dim3(NT / 64, NB * NH), 256, 0, stream>>>(qo, ko, vt, mask, oatt);
    gemm_out_kernel<<<dim3(NBT / 128, NC / 128), 256, 0, stream>>>(oatt, wpb, bp, mask, out);
    maskout_kernel<<<dim3(NBT / 256), 256, 0, stream>>>(mask, out);
}

// Round 2
// 266.547 us; speedup vs baseline: 1.1593x; 1.1593x over previous
//
#include <hip/hip_runtime.h>
#include <hip/hip_bf16.h>

// Problem constants (from reference)
#define NB 2
#define NC 1024
#define NT 1536
#define NH 16
#define ND 64
#define NBT 3072   // NB*NT
#define ATTN_SCALE 0.125f
#define LN_EPS 1e-5f

typedef __attribute__((ext_vector_type(8))) __bf16 bf16x8;
typedef __attribute__((ext_vector_type(4))) float f32x4;
typedef __attribute__((ext_vector_type(16))) float f32x16;

__device__ __forceinline__ unsigned short f2bf(float f) {
    unsigned u = __float_as_uint(f);
    u += 0x7fffu + ((u >> 16) & 1u);   // round-to-nearest-even
    return (unsigned short)(u >> 16);
}
__device__ __forceinline__ float bf2f(unsigned short s) {
    return __uint_as_float(((unsigned)s) << 16);
}
__device__ __forceinline__ f32x4 mfma16(bf16x8 a, bf16x8 b, f32x4 c) {
    return __builtin_amdgcn_mfma_f32_16x16x32_bf16(a, b, c, 0, 0, 0);
}
__device__ __forceinline__ f32x16 mfma32(bf16x8 a, bf16x8 b, f32x16 c) {
    return __builtin_amdgcn_mfma_f32_32x32x16_bf16(a, b, c, 0, 0, 0);
}
__device__ __forceinline__ bf16x8 ldbf8(const unsigned short* p) {
    return *reinterpret_cast<const bf16x8*>(p);
}

// ---------------------------------------------------------------------------
// Convert f32 1024x1024 weights -> bf16 (so GEMMs can read bf16 fragments)
__global__ __launch_bounds__(256) void wcvt_kernel(
    const float* __restrict__ w0, const float* __restrict__ w1,
    const float* __restrict__ w2, const float* __restrict__ w3,
    unsigned short* __restrict__ o0, unsigned short* __restrict__ o1,
    unsigned short* __restrict__ o2, unsigned short* __restrict__ o3)
{
    const float* src; unsigned short* dst;
    switch (blockIdx.y) {
        case 0: src = w0; dst = o0; break;
        case 1: src = w1; dst = o1; break;
        case 2: src = w2; dst = o2; break;
        default: src = w3; dst = o3; break;
    }
    int i = (blockIdx.x * 256 + threadIdx.x) * 4;
    float4 v = *reinterpret_cast<const float4*>(src + i);
    ushort4 r;
    r.x = f2bf(v.x); r.y = f2bf(v.y); r.z = f2bf(v.z); r.w = f2bf(v.w);
    *reinterpret_cast<ushort4*>(dst + i) = r;
}

// ---------------------------------------------------------------------------
// Depthwise conv3 (pad 1) -> mask -> channel LayerNorm -> bf16, transposed
// output layout [bt][c].  grid (NT/16, NB, 3), block 256.
__global__ __launch_bounds__(256) void convln_kernel(
    const float* __restrict__ x, const float* __restrict__ y, const float* __restrict__ z,
    const float* __restrict__ qw, const float* __restrict__ kw, const float* __restrict__ vw,
    const float* __restrict__ qg, const float* __restrict__ qb,
    const float* __restrict__ kgm, const float* __restrict__ kbt,
    const float* __restrict__ vg, const float* __restrict__ vb,
    const int* __restrict__ mask,
    unsigned short* __restrict__ xn, unsigned short* __restrict__ yn,
    unsigned short* __restrict__ zn)
{
    __shared__ __align__(16) unsigned short tile[16 * 1032];
    __shared__ float psum[16][17], psq[16][17];
    __shared__ float smu[16], srs[16];

    const float* src; const float* cw; const float* g; const float* be;
    unsigned short* dst;
    if (blockIdx.z == 0)      { src = x; cw = qw; g = qg;  be = qb;  dst = xn; }
    else if (blockIdx.z == 1) { src = y; cw = kw; g = kgm; be = kbt; dst = yn; }
    else                      { src = z; cw = vw; g = vg;  be = vb;  dst = zn; }

    int b  = blockIdx.y;
    int t0 = blockIdx.x * 16;
    int tid = threadIdx.x;
    int tt = tid & 15, cc = tid >> 4;
    int t = t0 + tt;
    float mval = (mask[b * NT + t] != 0) ? 1.f : 0.f;

    const float* sb = src + (size_t)b * NC * NT;
    float sum = 0.f, ssq = 0.f;
    for (int c0 = 0; c0 < NC; c0 += 16) {
        int c = c0 + cc;
        const float* xp = sb + (size_t)c * NT;
        float v0 = xp[t];
        float vm = __shfl_up(v0, 1, 16);
        float vp = __shfl_down(v0, 1, 16);
        if (tt == 0)  vm = (t > 0)      ? xp[t - 1] : 0.f;
        if (tt == 15) vp = (t + 1 < NT) ? xp[t + 1] : 0.f;
        float w0 = cw[c * 3], w1 = cw[c * 3 + 1], w2 = cw[c * 3 + 2];
        float conv = (w0 * vm + w1 * v0 + w2 * vp) * mval;
        tile[tt * 1032 + c] = f2bf(conv);
        sum += conv; ssq += conv * conv;
    }
    psum[cc][tt] = sum; psq[cc][tt] = ssq;
    __syncthreads();
    if (tid < 16) {
        float s = 0.f, q2 = 0.f;
        for (int j = 0; j < 16; ++j) { s += psum[j][tid]; q2 += psq[j][tid]; }
        float mu = s * (1.f / 1024.f);
        float var = q2 * (1.f / 1024.f) - mu * mu;
        smu[tid] = mu;
        srs[tid] = rsqrtf(var + LN_EPS);
    }
    __syncthreads();

    int c4 = tid * 4;
    float g0 = g[c4], g1 = g[c4 + 1], g2 = g[c4 + 2], g3 = g[c4 + 3];
    float e0 = be[c4], e1 = be[c4 + 1], e2 = be[c4 + 2], e3 = be[c4 + 3];
    for (int r = 0; r < 16; ++r) {
        ushort4 tv = *reinterpret_cast<const ushort4*>(&tile[r * 1032 + c4]);
        float mu = smu[r], rs = srs[r];
        ushort4 o;
        o.x = f2bf((bf2f(tv.x) - mu) * rs * g0 + e0);
        o.y = f2bf((bf2f(tv.y) - mu) * rs * g1 + e1);
        o.z = f2bf((bf2f(tv.z) - mu) * rs * g2 + e2);
        o.w = f2bf((bf2f(tv.w) - mu) * rs * g3 + e3);
        *reinterpret_cast<ushort4*>(dst + (size_t)(b * NT + t0 + r) * NC + c4) = o;
    }
}

// ---------------------------------------------------------------------------
// q/k/v projections. grid (24, 8, 3), block 256 (4 waves, 2x2, 64x64/wave).
__global__ __launch_bounds__(256) void gemm_qkv_kernel(
    const unsigned short* __restrict__ wqb, const unsigned short* __restrict__ wkb,
    const unsigned short* __restrict__ wvb,
    const unsigned short* __restrict__ xn, const unsigned short* __restrict__ yn,
    const unsigned short* __restrict__ zn,
    const float* __restrict__ bq, const float* __restrict__ bk, const float* __restrict__ bv,
    unsigned short* __restrict__ qo, unsigned short* __restrict__ ko,
    unsigned short* __restrict__ vt)
{
    int which = blockIdx.z;
    const unsigned short* W = (which == 0) ? wqb : (which == 1) ? wkb : wvb;
    const unsigned short* X = (which == 0) ? xn : (which == 1) ? yn : zn;
    const float* bias = (which == 0) ? bq : (which == 1) ? bk : bv;

    int lane = threadIdx.x & 63, w = threadIdx.x >> 6;
    int wm = w >> 1, wn = w & 1;
    int ob = blockIdx.y * 128 + wm * 64;
    int nb = blockIdx.x * 128 + wn * 64;
    int r0 = lane & 15, kg = lane >> 4;

    f32x4 acc[4][4];
    #pragma unroll
    for (int i = 0; i < 4; ++i)
        #pragma unroll
        for (int j = 0; j < 4; ++j) acc[i][j] = (f32x4){0.f, 0.f, 0.f, 0.f};

    const unsigned short* Ap = W + (size_t)(ob + r0) * NC + kg * 8;
    const unsigned short* Bp = X + (size_t)(nb + r0) * NC + kg * 8;

    for (int k0 = 0; k0 < NC; k0 += 32) {
        bf16x8 a[4], bb[4];
        #pragma unroll
        for (int i = 0; i < 4; ++i) a[i]  = ldbf8(Ap + (size_t)i * 16 * NC + k0);
        #pragma unroll
        for (int i = 0; i < 4; ++i) bb[i] = ldbf8(Bp + (size_t)i * 16 * NC + k0);
        #pragma unroll
        for (int mf = 0; mf < 4; ++mf)
            #pragma unroll
            for (int nf = 0; nf < 4; ++nf)
                acc[mf][nf] = mfma16(a[mf], bb[nf], acc[mf][nf]);
    }

    if (which < 2) {
        unsigned short* OUT = (which == 0) ? qo : ko;
        #pragma unroll
        for (int mf = 0; mf < 4; ++mf) {
            int o0 = ob + mf * 16 + kg * 4;
            float4 bz = *reinterpret_cast<const float4*>(bias + o0);
            #pragma unroll
            for (int nf = 0; nf < 4; ++nf) {
                int n = nb + nf * 16 + r0;
                ushort4 st;
                st.x = f2bf(acc[mf][nf][0] + bz.x);
                st.y = f2bf(acc[mf][nf][1] + bz.y);
                st.z = f2bf(acc[mf][nf][2] + bz.z);
                st.w = f2bf(acc[mf][nf][3] + bz.w);
                *reinterpret_cast<ushort4*>(OUT + (size_t)n * NC + o0) = st;
            }
        }
    } else {
        #pragma unroll
        for (int mf = 0; mf < 4; ++mf) {
            int o0 = ob + mf * 16 + kg * 4;
            #pragma unroll
            for (int nf = 0; nf < 4; ++nf) {
                int n = nb + nf * 16 + r0;
                #pragma unroll
                for (int r = 0; r < 4; ++r)
                    vt[(size_t)(o0 + r) * NBT + n] = f2bf(acc[mf][nf][r] + bias[o0 + r]);
            }
        }
    }
}

// ---------------------------------------------------------------------------
// Flash attention, swapped-operand 32x32x16 structure (lane-local softmax).
// grid (NT/128, NB*NH), block 256 = 4 independent waves x 32 q-rows. No LDS.
// q,k: [bt][c] bf16; vt: [c][bt] bf16; output oatt: [bt][c] bf16.
__global__ __launch_bounds__(256) void attn_kernel(
    const unsigned short* __restrict__ q, const unsigned short* __restrict__ kk,
    const unsigned short* __restrict__ vt, const int* __restrict__ mask,
    unsigned short* __restrict__ oatt)
{
    int lane = threadIdx.x & 63;
    int w = threadIdx.x >> 6;
    int b = blockIdx.y >> 4, h = blockIdx.y & 15;
    int q0 = blockIdx.x * 128 + w * 32;
    int ql = lane & 31;          // q column this lane owns
    int hi = lane >> 5;          // half-wave (k/d sub-slice)

    const int* mrow = mask + b * NT;
    int valid = 0;
    #pragma unroll
    for (int i = 0; i < NT / 64; ++i)
        valid += __popcll(__ballot(mrow[lane + 64 * i] != 0));
    if (q0 >= valid) return;     // masked q rows: oatt never observed downstream
    int ntiles = (valid + 31) >> 5;

    // Q fragments (B-operand rows = q), loaded once: 4 d-slices of 16
    const unsigned short* qp = q + (size_t)(b * NT + q0 + ql) * NC + h * ND + hi * 8;
    bf16x8 qf[4];
    #pragma unroll
    for (int dd = 0; dd < 4; ++dd) qf[dd] = ldbf8(qp + dd * 16);

    const f32x16 z16 = {0.f,0.f,0.f,0.f, 0.f,0.f,0.f,0.f, 0.f,0.f,0.f,0.f, 0.f,0.f,0.f,0.f};
    f32x16 o0 = z16, o1 = z16;   // O^T: q = ql, d = blk*32 + (r&3)+8*(r>>2)+4*hi
    float m = -1e30f, l = 0.f;

    const unsigned short* kbase = kk + (size_t)(b * NT) * NC + h * ND + hi * 8;
    const unsigned short* vbase = vt + (size_t)(h * ND) * NBT + b * NT + hi * 8;

    bf16x8 kf[4];
    #pragma unroll
    for (int dd = 0; dd < 4; ++dd) kf[dd] = ldbf8(kbase + (size_t)ql * NC + dd * 16);

    for (int t = 0; t < ntiles; ++t) {
        int kb = t * 32;
        // S^T = K Q^T : lane holds S[k-spread][q=ql], 16 regs
        f32x16 s = z16;
        #pragma unroll
        for (int dd = 0; dd < 4; ++dd) s = mfma32(kf[dd], qf[dd], s);

        // prefetch next K tile into registers
        if (t + 1 < ntiles) {
            #pragma unroll
            for (int dd = 0; dd < 4; ++dd)
                kf[dd] = ldbf8(kbase + (size_t)(kb + 32 + ql) * NC + dd * 16);
        }
        // V fragments for this tile (A-operand rows = d)
        bf16x8 vf[2][2];
        #pragma unroll
        for (int d0 = 0; d0 < 2; ++d0)
            #pragma unroll
            for (int ks = 0; ks < 2; ++ks)
                vf[d0][ks] = ldbf8(vbase + (size_t)(d0 * 32 + ql) * NBT + kb + ks * 16);

        // scale + prefix-mask + per-lane row max (q is lane-local)
        bool tail = (kb + 32 > valid);
        float pmax = -1e30f;
        #pragma unroll
        for (int r = 0; r < 16; ++r) {
            float sv = s[r] * ATTN_SCALE;
            if (tail) {
                int kg = kb + (r & 3) + 8 * (r >> 2) + 4 * hi;
                sv = (kg < valid) ? sv : -1e30f;
            }
            s[r] = sv;
            pmax = fmaxf(pmax, sv);
        }
        pmax = fmaxf(pmax, __shfl_xor(pmax, 32));

        if (__any(pmax > m)) {           // defer-max: skip rescale when possible
            float mn = fmaxf(m, pmax);
            float scale = __expf(m - mn);
            m = mn;
            l *= scale;
            o0 *= scale; o1 *= scale;
        }

        // P = exp(S-m), pack to bf16 pairs, exchange halves for B-fragments
        float rs = 0.f;
        unsigned cpk[8];
        #pragma unroll
        for (int i = 0; i < 8; ++i) {
            float pa = __expf(s[2 * i]     - m);
            float pb = __expf(s[2 * i + 1] - m);
            rs += pa + pb;
            cpk[i] = ((unsigned)f2bf(pb) << 16) | (unsigned)f2bf(pa);
        }
        rs += __shfl_xor(rs, 32);
        l += rs;

        unsigned dpk[8];
        #pragma unroll
        for (int i = 0; i < 8; ++i) dpk[i] = __shfl_xor(cpk[i], 32);

        union { unsigned u[4]; bf16x8 v; } A0, A1;
        A0.u[0] = hi ? dpk[2] : cpk[0];
        A0.u[1] = hi ? dpk[3] : cpk[1];
        A0.u[2] = hi ? cpk[2] : dpk[0];
        A0.u[3] = hi ? cpk[3] : dpk[1];
        A1.u[0] = hi ? dpk[6] : cpk[4];
        A1.u[1] = hi ? dpk[7] : cpk[5];
        A1.u[2] = hi ? cpk[6] : dpk[4];
        A1.u[3] = hi ? cpk[7] : dpk[5];

        // O^T += V^T P : keeps q lane-local (matches softmax state)
        o0 = mfma32(vf[0][0], A0.v, o0);
        o0 = mfma32(vf[0][1], A1.v, o0);
        o1 = mfma32(vf[1][0], A0.v, o1);
        o1 = mfma32(vf[1][1], A1.v, o1);
    }

    float inv = (l > 0.f) ? (1.f / l) : 0.f;
    unsigned short* ob = oatt + (size_t)(b * NT + q0 + ql) * NC + h * ND;
    #pragma unroll
    for (int g = 0; g < 4; ++g) {
        ushort4 s0, s1;
        s0.x = f2bf(o0[4 * g + 0] * inv); s0.y = f2bf(o0[4 * g + 1] * inv);
        s0.z = f2bf(o0[4 * g + 2] * inv); s0.w = f2bf(o0[4 * g + 3] * inv);
        s1.x = f2bf(o1[4 * g + 0] * inv); s1.y = f2bf(o1[4 * g + 1] * inv);
        s1.z = f2bf(o1[4 * g + 2] * inv); s1.w = f2bf(o1[4 * g + 3] * inv);
        *reinterpret_cast<ushort4*>(ob + g * 8 + 4 * hi)      = s0;
        *reinterpret_cast<ushort4*>(ob + 32 + g * 8 + 4 * hi) = s1;
    }
}

// ---------------------------------------------------------------------------
// Output projection, role-swapped (M = bt) so stores run contiguous along T.
__global__ __launch_bounds__(256) void gemm_out_kernel(
    const unsigned short* __restrict__ oatt, const unsigned short* __restrict__ wpb,
    const float* __restrict__ bp, const int* __restrict__ mask,
    float* __restrict__ out)
{
    int lane = threadIdx.x & 63, w = threadIdx.x >> 6;
    int wm = w >> 1, wn = w & 1;
    int mb  = blockIdx.x * 128 + wm * 64;
    int obb = blockIdx.y * 128 + wn * 64;
    int r0 = lane & 15, kg = lane >> 4;

    f32x4 acc[4][4];
    #pragma unroll
    for (int i = 0; i < 4; ++i)
        #pragma unroll
        for (int j = 0; j < 4; ++j) acc[i][j] = (f32x4){0.f, 0.f, 0.f, 0.f};

    const unsigned short* Ap = oatt + (size_t)(mb + r0) * NC + kg * 8;
    const unsigned short* Bp = wpb + (size_t)(obb + r0) * NC + kg * 8;

    for (int k0 = 0; k0 < NC; k0 += 32) {
        bf16x8 a[4], bb[4];
        #pragma unroll
        for (int i = 0; i < 4; ++i) a[i]  = ldbf8(Ap + (size_t)i * 16 * NC + k0);
        #pragma unroll
        for (int i = 0; i < 4; ++i) bb[i] = ldbf8(Bp + (size_t)i * 16 * NC + k0);
        #pragma unroll
        for (int mf = 0; mf < 4; ++mf)
            #pragma unroll
            for (int nf = 0; nf < 4; ++nf)
                acc[mf][nf] = mfma16(a[mf], bb[nf], acc[mf][nf]);
    }

    int b_ = (int)(blockIdx.x >= 12);
    size_t obase = (size_t)b_ * NC * NT;
    #pragma unroll
    for (int mf = 0; mf < 4; ++mf) {
        int bt0 = mb + mf * 16 + kg * 4;
        int4 mv = *reinterpret_cast<const int4*>(mask + bt0);
        float m0 = mv.x ? 1.f : 0.f;
        float m1 = mv.y ? 1.f : 0.f;
        float m2 = mv.z ? 1.f : 0.f;
        float m3 = mv.w ? 1.f : 0.f;
        int t0 = bt0 - b_ * NT;
        #pragma unroll
        for (int nf = 0; nf < 4; ++nf) {
            int o = obb + nf * 16 + r0;
            float bz = bp[o];
            f32x4 vv;
            vv[0] = (acc[mf][nf][0] + bz) * m0;
            vv[1] = (acc[mf][nf][1] + bz) * m1;
            vv[2] = (acc[mf][nf][2] + bz) * m2;
            vv[3] = (acc[mf][nf][3] + bz) * m3;
            *reinterpret_cast<f32x4*>(out + obase + (size_t)o * NT + t0) = vv;
        }
    }
}

// ---------------------------------------------------------------------------
__global__ __launch_bounds__(256) void maskout_kernel(const int* __restrict__ mask,
                                                      float* __restrict__ out)
{
    int i = blockIdx.x * 256 + threadIdx.x;
    if (i < NBT) out[(size_t)NB * NC * NT + i] = (mask[i] != 0) ? 1.f : 0.f;
}

// ---------------------------------------------------------------------------
extern "C" void kernel_launch(void* const* d_in, const int* in_sizes, int n_in,
                              void* d_out, int out_size, void* d_ws, size_t ws_size,
                              hipStream_t stream)
{
    const float* x    = (const float*)d_in[0];
    const float* y    = (const float*)d_in[1];
    const float* z    = (const float*)d_in[2];
    const int*   mask = (const int*)d_in[3];
    const float* qw   = (const float*)d_in[4];
    const float* kw   = (const float*)d_in[5];
    const float* vw   = (const float*)d_in[6];
    const float* qg   = (const float*)d_in[7];
    const float* qb   = (const float*)d_in[8];
    const float* kgm  = (const float*)d_in[9];
    const float* kbt  = (const float*)d_in[10];
    const float* vg   = (const float*)d_in[11];
    const float* vb   = (const float*)d_in[12];
    const float* wq   = (const float*)d_in[13];
    const float* bq   = (const float*)d_in[14];
    const float* wk   = (const float*)d_in[15];
    const float* bk   = (const float*)d_in[16];
    const float* wv   = (const float*)d_in[17];
    const float* bv   = (const float*)d_in[18];
    const float* wp   = (const float*)d_in[19];
    const float* bp   = (const float*)d_in[20];

    unsigned short* xn  = (unsigned short*)d_ws;
    unsigned short* yn  = xn + (size_t)NBT * NC;
    unsigned short* zn  = yn + (size_t)NBT * NC;
    unsigned short* qo  = zn + (size_t)NBT * NC;
    unsigned short* ko  = qo + (size_t)NBT * NC;
    unsigned short* vt  = ko + (size_t)NBT * NC;
    unsigned short* wqb = vt + (size_t)NBT * NC;
    unsigned short* wkb = wqb + (size_t)NC * NC;
    unsigned short* wvb = wkb + (size_t)NC * NC;
    unsigned short* wpb = wvb + (size_t)NC * NC;
    unsigned short* oatt = xn;  // xn dead after gemm_qkv; reuse for attention out

    float* out = (float*)d_out;

    wcvt_kernel<<<dim3(1024, 4), 256, 0, stream>>>(wq, wk, wv, wp, wqb, wkb, wvb, wpb);
    convln_kernel<<<dim3(NT / 16, NB, 3), 256, 0, stream>>>(
        x, y, z, qw, kw, vw, qg, qb, kgm, kbt, vg, vb, mask, xn, yn, zn);
    gemm_qkv_kernel<<<dim3(NBT / 128, NC / 128, 3), 256, 0, stream>>>(
        wqb, wkb, wvb, xn, yn, zn, bq, bk, bv, qo, ko, vt);
    attn_kernel<<<dim3(NT / 128, NB * NH), 256, 0, stream>>>(qo, ko, vt, mask, oatt);
    gemm_out_kernel<<<dim3(NBT / 128, NC / 128), 256, 0, stream>>>(oatt, wpb, bp, mask, out);
    maskout_kernel<<<dim3(NBT / 256), 256, 0, stream>>>(mask, out);
}

// Round 3
// 197.846 us; speedup vs baseline: 1.5618x; 1.3472x over previous
//
#include <hip/hip_runtime.h>
#include <hip/hip_bf16.h>

// Problem constants (from reference)
#define NB 2
#define NC 1024
#define NT 1536
#define NH 16
#define ND 64
#define NBT 3072   // NB*NT
#define ATTN_SCALE 0.125f
#define LN_EPS 1e-5f
#define BK 32      // GEMM K-step

typedef __attribute__((ext_vector_type(8))) __bf16 bf16x8;
typedef __attribute__((ext_vector_type(4))) float f32x4;
typedef __attribute__((ext_vector_type(16))) float f32x16;

__device__ __forceinline__ unsigned short f2bf(float f) {
    unsigned u = __float_as_uint(f);
    u += 0x7fffu + ((u >> 16) & 1u);   // round-to-nearest-even
    return (unsigned short)(u >> 16);
}
__device__ __forceinline__ float bf2f(unsigned short s) {
    return __uint_as_float(((unsigned)s) << 16);
}
__device__ __forceinline__ f32x4 mfma16(bf16x8 a, bf16x8 b, f32x4 c) {
    return __builtin_amdgcn_mfma_f32_16x16x32_bf16(a, b, c, 0, 0, 0);
}
__device__ __forceinline__ f32x16 mfma32(bf16x8 a, bf16x8 b, f32x16 c) {
    return __builtin_amdgcn_mfma_f32_32x32x16_bf16(a, b, c, 0, 0, 0);
}
__device__ __forceinline__ bf16x8 ldbf8(const unsigned short* p) {
    return *reinterpret_cast<const bf16x8*>(p);
}
// async global->LDS, 16B per lane; LDS dest = uniform base + lane*16
__device__ __forceinline__ void gload16(const void* g, void* l) {
    __builtin_amdgcn_global_load_lds(
        (const __attribute__((address_space(1))) void*)g,
        (__attribute__((address_space(3))) void*)l, 16, 0, 0);
}
#define WAITV(n) asm volatile("s_waitcnt vmcnt(" #n ")" ::: "memory")
#define BAR()    do { __builtin_amdgcn_s_barrier(); asm volatile("" ::: "memory"); } while (0)

// ---------------------------------------------------------------------------
// Convert f32 1024x1024 weights -> bf16
__global__ __launch_bounds__(256) void wcvt_kernel(
    const float* __restrict__ w0, const float* __restrict__ w1,
    const float* __restrict__ w2, const float* __restrict__ w3,
    unsigned short* __restrict__ o0, unsigned short* __restrict__ o1,
    unsigned short* __restrict__ o2, unsigned short* __restrict__ o3)
{
    const float* src; unsigned short* dst;
    switch (blockIdx.y) {
        case 0: src = w0; dst = o0; break;
        case 1: src = w1; dst = o1; break;
        case 2: src = w2; dst = o2; break;
        default: src = w3; dst = o3; break;
    }
    int i = (blockIdx.x * 256 + threadIdx.x) * 4;
    float4 v = *reinterpret_cast<const float4*>(src + i);
    ushort4 r;
    r.x = f2bf(v.x); r.y = f2bf(v.y); r.z = f2bf(v.z); r.w = f2bf(v.w);
    *reinterpret_cast<ushort4*>(dst + i) = r;
}

// ---------------------------------------------------------------------------
// Depthwise conv3 (pad 1) -> mask -> channel LayerNorm -> bf16, [bt][c]
__global__ __launch_bounds__(256) void convln_kernel(
    const float* __restrict__ x, const float* __restrict__ y, const float* __restrict__ z,
    const float* __restrict__ qw, const float* __restrict__ kw, const float* __restrict__ vw,
    const float* __restrict__ qg, const float* __restrict__ qb,
    const float* __restrict__ kgm, const float* __restrict__ kbt,
    const float* __restrict__ vg, const float* __restrict__ vb,
    const int* __restrict__ mask,
    unsigned short* __restrict__ xn, unsigned short* __restrict__ yn,
    unsigned short* __restrict__ zn)
{
    __shared__ __align__(16) unsigned short tile[16 * 1032];
    __shared__ float psum[16][17], psq[16][17];
    __shared__ float smu[16], srs[16];

    const float* src; const float* cw; const float* g; const float* be;
    unsigned short* dst;
    if (blockIdx.z == 0)      { src = x; cw = qw; g = qg;  be = qb;  dst = xn; }
    else if (blockIdx.z == 1) { src = y; cw = kw; g = kgm; be = kbt; dst = yn; }
    else                      { src = z; cw = vw; g = vg;  be = vb;  dst = zn; }

    int b  = blockIdx.y;
    int t0 = blockIdx.x * 16;
    int tid = threadIdx.x;
    int tt = tid & 15, cc = tid >> 4;
    int t = t0 + tt;
    float mval = (mask[b * NT + t] != 0) ? 1.f : 0.f;

    const float* sb = src + (size_t)b * NC * NT;
    float sum = 0.f, ssq = 0.f;
    for (int c0 = 0; c0 < NC; c0 += 16) {
        int c = c0 + cc;
        const float* xp = sb + (size_t)c * NT;
        float v0 = xp[t];
        float vm = __shfl_up(v0, 1, 16);
        float vp = __shfl_down(v0, 1, 16);
        if (tt == 0)  vm = (t > 0)      ? xp[t - 1] : 0.f;
        if (tt == 15) vp = (t + 1 < NT) ? xp[t + 1] : 0.f;
        float w0 = cw[c * 3], w1 = cw[c * 3 + 1], w2 = cw[c * 3 + 2];
        float conv = (w0 * vm + w1 * v0 + w2 * vp) * mval;
        tile[tt * 1032 + c] = f2bf(conv);
        sum += conv; ssq += conv * conv;
    }
    psum[cc][tt] = sum; psq[cc][tt] = ssq;
    __syncthreads();
    if (tid < 16) {
        float s = 0.f, q2 = 0.f;
        for (int j = 0; j < 16; ++j) { s += psum[j][tid]; q2 += psq[j][tid]; }
        float mu = s * (1.f / 1024.f);
        float var = q2 * (1.f / 1024.f) - mu * mu;
        smu[tid] = mu;
        srs[tid] = rsqrtf(var + LN_EPS);
    }
    __syncthreads();

    int c4 = tid * 4;
    float g0 = g[c4], g1 = g[c4 + 1], g2 = g[c4 + 2], g3 = g[c4 + 3];
    float e0 = be[c4], e1 = be[c4 + 1], e2 = be[c4 + 2], e3 = be[c4 + 3];
    for (int r = 0; r < 16; ++r) {
        ushort4 tv = *reinterpret_cast<const ushort4*>(&tile[r * 1032 + c4]);
        float mu = smu[r], rs = srs[r];
        ushort4 o;
        o.x = f2bf((bf2f(tv.x) - mu) * rs * g0 + e0);
        o.y = f2bf((bf2f(tv.y) - mu) * rs * g1 + e1);
        o.z = f2bf((bf2f(tv.z) - mu) * rs * g2 + e2);
        o.w = f2bf((bf2f(tv.w) - mu) * rs * g3 + e3);
        *reinterpret_cast<ushort4*>(dst + (size_t)(b * NT + t0 + r) * NC + c4) = o;
    }
}

// ---------------------------------------------------------------------------
// q/k/v projections, LDS-staged 2-phase double-buffered (m97/T3-min structure).
// grid (24, 8, 3), block 256 (4 waves, 2x2, 64x64/wave).
__global__ __launch_bounds__(256) void gemm_qkv_kernel(
    const unsigned short* __restrict__ wqb, const unsigned short* __restrict__ wkb,
    const unsigned short* __restrict__ wvb,
    const unsigned short* __restrict__ xn, const unsigned short* __restrict__ yn,
    const unsigned short* __restrict__ zn,
    const float* __restrict__ bq, const float* __restrict__ bk, const float* __restrict__ bv,
    unsigned short* __restrict__ qo, unsigned short* __restrict__ ko,
    unsigned short* __restrict__ vt)
{
    __shared__ __align__(16) unsigned short lX[2][128 * BK];  // X tile (bt rows)
    __shared__ __align__(16) unsigned short lW[2][128 * BK];  // W tile (o rows)

    int which = blockIdx.z;
    const unsigned short* W = (which == 0) ? wqb : (which == 1) ? wkb : wvb;
    const unsigned short* X = (which == 0) ? xn : (which == 1) ? yn : zn;
    const float* bias = (which == 0) ? bq : (which == 1) ? bk : bv;

    int tid = threadIdx.x;
    int lane = tid & 63, w = tid >> 6;
    int nb = blockIdx.x * 128;   // bt tile base
    int ob = blockIdx.y * 128;   // out-channel tile base

    // staging: wave-issue covers 16 rows x 64B; lane -> row lane>>2, 16B chunk lane&3
    int srow = w * 16 + (lane >> 2);
    const unsigned short* gX = X + (size_t)(nb + srow) * NC + (lane & 3) * 8;
    const unsigned short* gW = W + (size_t)(ob + srow) * NC + (lane & 3) * 8;
    unsigned short* lX0 = &lX[0][0] + w * 16 * BK;
    unsigned short* lW0 = &lW[0][0] + w * 16 * BK;

#define QKV_STAGE(buf, k0) do {                                       \
    gload16(gX + (k0),           lX0 + (buf) * 128 * BK);             \
    gload16(gX + (k0) + 64 * NC, lX0 + (buf) * 128 * BK + 64 * BK);   \
    gload16(gW + (k0),           lW0 + (buf) * 128 * BK);             \
    gload16(gW + (k0) + 64 * NC, lW0 + (buf) * 128 * BK + 64 * BK);   \
} while (0)

    int r0 = lane & 15, kg = lane >> 4;
    const unsigned short* fW = &lW[0][0] + ((w & 1)  * 64 + r0) * BK + kg * 8;
    const unsigned short* fX = &lX[0][0] + ((w >> 1) * 64 + r0) * BK + kg * 8;

    f32x4 acc[4][4];
    #pragma unroll
    for (int i = 0; i < 4; ++i)
        #pragma unroll
        for (int j = 0; j < 4; ++j) acc[i][j] = (f32x4){0.f, 0.f, 0.f, 0.f};

#define QKV_COMPUTE(buf) do {                                                  \
    bf16x8 a_[4], b_[4];                                                       \
    _Pragma("unroll") for (int i = 0; i < 4; ++i)                              \
        a_[i] = ldbf8(fW + (buf) * 128 * BK + i * 16 * BK);                    \
    _Pragma("unroll") for (int i = 0; i < 4; ++i)                              \
        b_[i] = ldbf8(fX + (buf) * 128 * BK + i * 16 * BK);                    \
    _Pragma("unroll") for (int mf = 0; mf < 4; ++mf)                           \
        _Pragma("unroll") for (int nf = 0; nf < 4; ++nf)                       \
            acc[mf][nf] = mfma16(a_[mf], b_[nf], acc[mf][nf]);                 \
} while (0)

    QKV_STAGE(0, 0);
    #pragma unroll 1
    for (int k0 = 0; k0 < NC - 2 * BK; k0 += 2 * BK) {
        QKV_STAGE(1, k0 + BK);
        WAITV(4); BAR();
        QKV_COMPUTE(0);
        BAR();
        QKV_STAGE(0, k0 + 2 * BK);
        WAITV(4); BAR();
        QKV_COMPUTE(1);
        BAR();
    }
    QKV_STAGE(1, NC - BK);
    WAITV(4); BAR();
    QKV_COMPUTE(0);
    WAITV(0); BAR();
    QKV_COMPUTE(1);

    if (which < 2) {
        unsigned short* OUT = (which == 0) ? qo : ko;
        #pragma unroll
        for (int mf = 0; mf < 4; ++mf) {
            int o0 = ob + (w & 1) * 64 + mf * 16 + kg * 4;
            float4 bz = *reinterpret_cast<const float4*>(bias + o0);
            #pragma unroll
            for (int nf = 0; nf < 4; ++nf) {
                int n = nb + (w >> 1) * 64 + nf * 16 + r0;
                ushort4 st;
                st.x = f2bf(acc[mf][nf][0] + bz.x);
                st.y = f2bf(acc[mf][nf][1] + bz.y);
                st.z = f2bf(acc[mf][nf][2] + bz.z);
                st.w = f2bf(acc[mf][nf][3] + bz.w);
                *reinterpret_cast<ushort4*>(OUT + (size_t)n * NC + o0) = st;
            }
        }
    } else {
        #pragma unroll
        for (int mf = 0; mf < 4; ++mf) {
            int o0 = ob + (w & 1) * 64 + mf * 16 + kg * 4;
            #pragma unroll
            for (int nf = 0; nf < 4; ++nf) {
                int n = nb + (w >> 1) * 64 + nf * 16 + r0;
                #pragma unroll
                for (int r = 0; r < 4; ++r)
                    vt[(size_t)(o0 + r) * NBT + n] = f2bf(acc[mf][nf][r] + bias[o0 + r]);
            }
        }
    }
#undef QKV_STAGE
#undef QKV_COMPUTE
}

// ---------------------------------------------------------------------------
// Flash attention, swapped-operand 32x32x16 (lane-local softmax). Unchanged.
__global__ __launch_bounds__(256) void attn_kernel(
    const unsigned short* __restrict__ q, const unsigned short* __restrict__ kk,
    const unsigned short* __restrict__ vt, const int* __restrict__ mask,
    unsigned short* __restrict__ oatt)
{
    int lane = threadIdx.x & 63;
    int w = threadIdx.x >> 6;
    int b = blockIdx.y >> 4, h = blockIdx.y & 15;
    int q0 = blockIdx.x * 128 + w * 32;
    int ql = lane & 31;
    int hi = lane >> 5;

    const int* mrow = mask + b * NT;
    int valid = 0;
    #pragma unroll
    for (int i = 0; i < NT / 64; ++i)
        valid += __popcll(__ballot(mrow[lane + 64 * i] != 0));
    if (q0 >= valid) return;
    int ntiles = (valid + 31) >> 5;

    const unsigned short* qp = q + (size_t)(b * NT + q0 + ql) * NC + h * ND + hi * 8;
    bf16x8 qf[4];
    #pragma unroll
    for (int dd = 0; dd < 4; ++dd) qf[dd] = ldbf8(qp + dd * 16);

    const f32x16 z16 = {0.f,0.f,0.f,0.f, 0.f,0.f,0.f,0.f, 0.f,0.f,0.f,0.f, 0.f,0.f,0.f,0.f};
    f32x16 o0 = z16, o1 = z16;
    float m = -1e30f, l = 0.f;

    const unsigned short* kbase = kk + (size_t)(b * NT) * NC + h * ND + hi * 8;
    const unsigned short* vbase = vt + (size_t)(h * ND) * NBT + b * NT + hi * 8;

    bf16x8 kf[4];
    #pragma unroll
    for (int dd = 0; dd < 4; ++dd) kf[dd] = ldbf8(kbase + (size_t)ql * NC + dd * 16);

    for (int t = 0; t < ntiles; ++t) {
        int kb = t * 32;
        f32x16 s = z16;
        #pragma unroll
        for (int dd = 0; dd < 4; ++dd) s = mfma32(kf[dd], qf[dd], s);

        if (t + 1 < ntiles) {
            #pragma unroll
            for (int dd = 0; dd < 4; ++dd)
                kf[dd] = ldbf8(kbase + (size_t)(kb + 32 + ql) * NC + dd * 16);
        }
        bf16x8 vf[2][2];
        #pragma unroll
        for (int d0 = 0; d0 < 2; ++d0)
            #pragma unroll
            for (int ks = 0; ks < 2; ++ks)
                vf[d0][ks] = ldbf8(vbase + (size_t)(d0 * 32 + ql) * NBT + kb + ks * 16);

        bool tail = (kb + 32 > valid);
        float pmax = -1e30f;
        #pragma unroll
        for (int r = 0; r < 16; ++r) {
            float sv = s[r] * ATTN_SCALE;
            if (tail) {
                int kg = kb + (r & 3) + 8 * (r >> 2) + 4 * hi;
                sv = (kg < valid) ? sv : -1e30f;
            }
            s[r] = sv;
            pmax = fmaxf(pmax, sv);
        }
        pmax = fmaxf(pmax, __shfl_xor(pmax, 32));

        if (__any(pmax > m)) {
            float mn = fmaxf(m, pmax);
            float scale = __expf(m - mn);
            m = mn;
            l *= scale;
            o0 *= scale; o1 *= scale;
        }

        float rs = 0.f;
        unsigned cpk[8];
        #pragma unroll
        for (int i = 0; i < 8; ++i) {
            float pa = __expf(s[2 * i]     - m);
            float pb = __expf(s[2 * i + 1] - m);
            rs += pa + pb;
            cpk[i] = ((unsigned)f2bf(pb) << 16) | (unsigned)f2bf(pa);
        }
        rs += __shfl_xor(rs, 32);
        l += rs;

        unsigned dpk[8];
        #pragma unroll
        for (int i = 0; i < 8; ++i) dpk[i] = __shfl_xor(cpk[i], 32);

        union { unsigned u[4]; bf16x8 v; } A0, A1;
        A0.u[0] = hi ? dpk[2] : cpk[0];
        A0.u[1] = hi ? dpk[3] : cpk[1];
        A0.u[2] = hi ? cpk[2] : dpk[0];
        A0.u[3] = hi ? cpk[3] : dpk[1];
        A1.u[0] = hi ? dpk[6] : cpk[4];
        A1.u[1] = hi ? dpk[7] : cpk[5];
        A1.u[2] = hi ? cpk[6] : dpk[4];
        A1.u[3] = hi ? cpk[7] : dpk[5];

        o0 = mfma32(vf[0][0], A0.v, o0);
        o0 = mfma32(vf[0][1], A1.v, o0);
        o1 = mfma32(vf[1][0], A0.v, o1);
        o1 = mfma32(vf[1][1], A1.v, o1);
    }

    float inv = (l > 0.f) ? (1.f / l) : 0.f;
    unsigned short* ob = oatt + (size_t)(b * NT + q0 + ql) * NC + h * ND;
    #pragma unroll
    for (int g = 0; g < 4; ++g) {
        ushort4 s0, s1;
        s0.x = f2bf(o0[4 * g + 0] * inv); s0.y = f2bf(o0[4 * g + 1] * inv);
        s0.z = f2bf(o0[4 * g + 2] * inv); s0.w = f2bf(o0[4 * g + 3] * inv);
        s1.x = f2bf(o1[4 * g + 0] * inv); s1.y = f2bf(o1[4 * g + 1] * inv);
        s1.z = f2bf(o1[4 * g + 2] * inv); s1.w = f2bf(o1[4 * g + 3] * inv);
        *reinterpret_cast<ushort4*>(ob + g * 8 + 4 * hi)      = s0;
        *reinterpret_cast<ushort4*>(ob + 32 + g * 8 + 4 * hi) = s1;
    }
}

// ---------------------------------------------------------------------------
// Output projection, LDS-staged 2-phase; stores contiguous along T, fused mask.
// grid (24, 8), block 256.
__global__ __launch_bounds__(256) void gemm_out_kernel(
    const unsigned short* __restrict__ oatt, const unsigned short* __restrict__ wpb,
    const float* __restrict__ bp, const int* __restrict__ mask,
    float* __restrict__ out)
{
    __shared__ __align__(16) unsigned short lA[2][128 * BK];  // oatt tile (bt rows)
    __shared__ __align__(16) unsigned short lB[2][128 * BK];  // wp tile (o rows)

    int tid = threadIdx.x;
    int lane = tid & 63, w = tid >> 6;
    int mb  = blockIdx.x * 128;  // bt tile base
    int obb = blockIdx.y * 128;  // out-channel tile base

    int srow = w * 16 + (lane >> 2);
    const unsigned short* gA = oatt + (size_t)(mb + srow) * NC + (lane & 3) * 8;
    const unsigned short* gB = wpb + (size_t)(obb + srow) * NC + (lane & 3) * 8;
    unsigned short* lA0 = &lA[0][0] + w * 16 * BK;
    unsigned short* lB0 = &lB[0][0] + w * 16 * BK;

#define OUT_STAGE(buf, k0) do {                                       \
    gload16(gA + (k0),           lA0 + (buf) * 128 * BK);             \
    gload16(gA + (k0) + 64 * NC, lA0 + (buf) * 128 * BK + 64 * BK);   \
    gload16(gB + (k0),           lB0 + (buf) * 128 * BK);             \
    gload16(gB + (k0) + 64 * NC, lB0 + (buf) * 128 * BK + 64 * BK);   \
} while (0)

    int r0 = lane & 15, kg = lane >> 4;
    const unsigned short* fA = &lA[0][0] + ((w >> 1) * 64 + r0) * BK + kg * 8;
    const unsigned short* fB = &lB[0][0] + ((w & 1)  * 64 + r0) * BK + kg * 8;

    f32x4 acc[4][4];
    #pragma unroll
    for (int i = 0; i < 4; ++i)
        #pragma unroll
        for (int j = 0; j < 4; ++j) acc[i][j] = (f32x4){0.f, 0.f, 0.f, 0.f};

#define OUT_COMPUTE(buf) do {                                                  \
    bf16x8 a_[4], b_[4];                                                       \
    _Pragma("unroll") for (int i = 0; i < 4; ++i)                              \
        a_[i] = ldbf8(fA + (buf) * 128 * BK + i * 16 * BK);                    \
    _Pragma("unroll") for (int i = 0; i < 4; ++i)                              \
        b_[i] = ldbf8(fB + (buf) * 128 * BK + i * 16 * BK);                    \
    _Pragma("unroll") for (int mf = 0; mf < 4; ++mf)                           \
        _Pragma("unroll") for (int nf = 0; nf < 4; ++nf)                       \
            acc[mf][nf] = mfma16(a_[mf], b_[nf], acc[mf][nf]);                 \
} while (0)

    OUT_STAGE(0, 0);
    #pragma unroll 1
    for (int k0 = 0; k0 < NC - 2 * BK; k0 += 2 * BK) {
        OUT_STAGE(1, k0 + BK);
        WAITV(4); BAR();
        OUT_COMPUTE(0);
        BAR();
        OUT_STAGE(0, k0 + 2 * BK);
        WAITV(4); BAR();
        OUT_COMPUTE(1);
        BAR();
    }
    OUT_STAGE(1, NC - BK);
    WAITV(4); BAR();
    OUT_COMPUTE(0);
    WAITV(0); BAR();
    OUT_COMPUTE(1);

    int b_ = (int)(blockIdx.x >= 12);
    size_t obase = (size_t)b_ * NC * NT;
    #pragma unroll
    for (int mf = 0; mf < 4; ++mf) {
        int bt0 = mb + (w >> 1) * 64 + mf * 16 + kg * 4;
        int4 mv = *reinterpret_cast<const int4*>(mask + bt0);
        float m0 = mv.x ? 1.f : 0.f;
        float m1 = mv.y ? 1.f : 0.f;
        float m2 = mv.z ? 1.f : 0.f;
        float m3 = mv.w ? 1.f : 0.f;
        int t0 = bt0 - b_ * NT;
        #pragma unroll
        for (int nf = 0; nf < 4; ++nf) {
            int o = obb + (w & 1) * 64 + nf * 16 + r0;
            float bz = bp[o];
            f32x4 vv;
            vv[0] = (acc[mf][nf][0] + bz) * m0;
            vv[1] = (acc[mf][nf][1] + bz) * m1;
            vv[2] = (acc[mf][nf][2] + bz) * m2;
            vv[3] = (acc[mf][nf][3] + bz) * m3;
            *reinterpret_cast<f32x4*>(out + obase + (size_t)o * NT + t0) = vv;
        }
    }
#undef OUT_STAGE
#undef OUT_COMPUTE
}

// ---------------------------------------------------------------------------
__global__ __launch_bounds__(256) void maskout_kernel(const int* __restrict__ mask,
                                                      float* __restrict__ out)
{
    int i = blockIdx.x * 256 + threadIdx.x;
    if (i < NBT) out[(size_t)NB * NC * NT + i] = (mask[i] != 0) ? 1.f : 0.f;
}

// ---------------------------------------------------------------------------
extern "C" void kernel_launch(void* const* d_in, const int* in_sizes, int n_in,
                              void* d_out, int out_size, void* d_ws, size_t ws_size,
                              hipStream_t stream)
{
    const float* x    = (const float*)d_in[0];
    const float* y    = (const float*)d_in[1];
    const float* z    = (const float*)d_in[2];
    const int*   mask = (const int*)d_in[3];
    const float* qw   = (const float*)d_in[4];
    const float* kw   = (const float*)d_in[5];
    const float* vw   = (const float*)d_in[6];
    const float* qg   = (const float*)d_in[7];
    const float* qb   = (const float*)d_in[8];
    const float* kgm  = (const float*)d_in[9];
    const float* kbt  = (const float*)d_in[10];
    const float* vg   = (const float*)d_in[11];
    const float* vb   = (const float*)d_in[12];
    const float* wq   = (const float*)d_in[13];
    const float* bq   = (const float*)d_in[14];
    const float* wk   = (const float*)d_in[15];
    const float* bk   = (const float*)d_in[16];
    const float* wv   = (const float*)d_in[17];
    const float* bv   = (const float*)d_in[18];
    const float* wp   = (const float*)d_in[19];
    const float* bp   = (const float*)d_in[20];

    unsigned short* xn  = (unsigned short*)d_ws;
    unsigned short* yn  = xn + (size_t)NBT * NC;
    unsigned short* zn  = yn + (size_t)NBT * NC;
    unsigned short* qo  = zn + (size_t)NBT * NC;
    unsigned short* ko  = qo + (size_t)NBT * NC;
    unsigned short* vt  = ko + (size_t)NBT * NC;
    unsigned short* wqb = vt + (size_t)NBT * NC;
    unsigned short* wkb = wqb + (size_t)NC * NC;
    unsigned short* wvb = wkb + (size_t)NC * NC;
    unsigned short* wpb = wvb + (size_t)NC * NC;
    unsigned short* oatt = xn;  // xn dead after gemm_qkv; reuse for attention out

    float* out = (float*)d_out;

    wcvt_kernel<<<dim3(1024, 4), 256, 0, stream>>>(wq, wk, wv, wp, wqb, wkb, wvb, wpb);
    convln_kernel<<<dim3(NT / 16, NB, 3), 256, 0, stream>>>(
        x, y, z, qw, kw, vw, qg, qb, kgm, kbt, vg, vb, mask, xn, yn, zn);
    gemm_qkv_kernel<<<dim3(NBT / 128, NC / 128, 3), 256, 0, stream>>>(
        wqb, wkb, wvb, xn, yn, zn, bq, bk, bv, qo, ko, vt);
    attn_kernel<<<dim3(NT / 128, NB * NH), 256, 0, stream>>>(qo, ko, vt, mask, oatt);
    gemm_out_kernel<<<dim3(NBT / 128, NC / 128), 256, 0, stream>>>(oatt, wpb, bp, mask, out);
    maskout_kernel<<<dim3(NBT / 256), 256, 0, stream>>>(mask, out);
}

// Round 4
// 186.662 us; speedup vs baseline: 1.6554x; 1.0599x over previous
//
#include <hip/hip_runtime.h>
#include <hip/hip_bf16.h>

// Problem constants (from reference)
#define NB 2
#define NC 1024
#define NT 1536
#define NH 16
#define ND 64
#define NBT 3072   // NB*NT
#define LN_EPS 1e-5f
#define BK 32      // GEMM K-step
// attention scale folded with log2(e): softmax computed in exp2 domain
#define QS2 0.18033688011112042f   // 0.125 * log2(e)

typedef __attribute__((ext_vector_type(8))) __bf16 bf16x8;
typedef __attribute__((ext_vector_type(4))) float f32x4;
typedef __attribute__((ext_vector_type(16))) float f32x16;

__device__ __forceinline__ unsigned short f2bf(float f) {
    unsigned u = __float_as_uint(f);
    u += 0x7fffu + ((u >> 16) & 1u);   // round-to-nearest-even
    return (unsigned short)(u >> 16);
}
__device__ __forceinline__ float bf2f(unsigned short s) {
    return __uint_as_float(((unsigned)s) << 16);
}
// pack two f32 -> packed bf16x2 (compiler emits v_cvt_pk_bf16_f32)
__device__ __forceinline__ unsigned pkbf(float a, float b) {
    union { __bf16 h[2]; unsigned u; } r;
    r.h[0] = (__bf16)a; r.h[1] = (__bf16)b;
    return r.u;
}
__device__ __forceinline__ float exp2fast(float x) {
    return __builtin_amdgcn_exp2f(x);
}
__device__ __forceinline__ f32x4 mfma16(bf16x8 a, bf16x8 b, f32x4 c) {
    return __builtin_amdgcn_mfma_f32_16x16x32_bf16(a, b, c, 0, 0, 0);
}
__device__ __forceinline__ f32x16 mfma32(bf16x8 a, bf16x8 b, f32x16 c) {
    return __builtin_amdgcn_mfma_f32_32x32x16_bf16(a, b, c, 0, 0, 0);
}
__device__ __forceinline__ bf16x8 ldbf8(const unsigned short* p) {
    return *reinterpret_cast<const bf16x8*>(p);
}
// async global->LDS, 16B per lane; LDS dest = uniform base + lane*16
__device__ __forceinline__ void gload16(const void* g, void* l) {
    __builtin_amdgcn_global_load_lds(
        (const __attribute__((address_space(1))) void*)g,
        (__attribute__((address_space(3))) void*)l, 16, 0, 0);
}
#define WAITV(n) asm volatile("s_waitcnt vmcnt(" #n ")" ::: "memory")
#define BAR()    do { __builtin_amdgcn_s_barrier(); asm volatile("" ::: "memory"); } while (0)

// ---------------------------------------------------------------------------
// Convert f32 1024x1024 weights -> bf16
__global__ __launch_bounds__(256) void wcvt_kernel(
    const float* __restrict__ w0, const float* __restrict__ w1,
    const float* __restrict__ w2, const float* __restrict__ w3,
    unsigned short* __restrict__ o0, unsigned short* __restrict__ o1,
    unsigned short* __restrict__ o2, unsigned short* __restrict__ o3)
{
    const float* src; unsigned short* dst;
    switch (blockIdx.y) {
        case 0: src = w0; dst = o0; break;
        case 1: src = w1; dst = o1; break;
        case 2: src = w2; dst = o2; break;
        default: src = w3; dst = o3; break;
    }
    int i = (blockIdx.x * 256 + threadIdx.x) * 4;
    float4 v = *reinterpret_cast<const float4*>(src + i);
    ushort4 r;
    r.x = f2bf(v.x); r.y = f2bf(v.y); r.z = f2bf(v.z); r.w = f2bf(v.w);
    *reinterpret_cast<ushort4*>(dst + i) = r;
}

// ---------------------------------------------------------------------------
// Depthwise conv3 (pad 1) -> mask -> channel LayerNorm -> bf16, [bt][c]
__global__ __launch_bounds__(256) void convln_kernel(
    const float* __restrict__ x, const float* __restrict__ y, const float* __restrict__ z,
    const float* __restrict__ qw, const float* __restrict__ kw, const float* __restrict__ vw,
    const float* __restrict__ qg, const float* __restrict__ qb,
    const float* __restrict__ kgm, const float* __restrict__ kbt,
    const float* __restrict__ vg, const float* __restrict__ vb,
    const int* __restrict__ mask,
    unsigned short* __restrict__ xn, unsigned short* __restrict__ yn,
    unsigned short* __restrict__ zn)
{
    __shared__ __align__(16) unsigned short tile[16 * 1032];
    __shared__ float psum[16][17], psq[16][17];
    __shared__ float smu[16], srs[16];

    const float* src; const float* cw; const float* g; const float* be;
    unsigned short* dst;
    if (blockIdx.z == 0)      { src = x; cw = qw; g = qg;  be = qb;  dst = xn; }
    else if (blockIdx.z == 1) { src = y; cw = kw; g = kgm; be = kbt; dst = yn; }
    else                      { src = z; cw = vw; g = vg;  be = vb;  dst = zn; }

    int b  = blockIdx.y;
    int t0 = blockIdx.x * 16;
    int tid = threadIdx.x;
    int tt = tid & 15, cc = tid >> 4;
    int t = t0 + tt;
    float mval = (mask[b * NT + t] != 0) ? 1.f : 0.f;

    const float* sb = src + (size_t)b * NC * NT;
    float sum = 0.f, ssq = 0.f;
    for (int c0 = 0; c0 < NC; c0 += 16) {
        int c = c0 + cc;
        const float* xp = sb + (size_t)c * NT;
        float v0 = xp[t];
        float vm = __shfl_up(v0, 1, 16);
        float vp = __shfl_down(v0, 1, 16);
        if (tt == 0)  vm = (t > 0)      ? xp[t - 1] : 0.f;
        if (tt == 15) vp = (t + 1 < NT) ? xp[t + 1] : 0.f;
        float w0 = cw[c * 3], w1 = cw[c * 3 + 1], w2 = cw[c * 3 + 2];
        float conv = (w0 * vm + w1 * v0 + w2 * vp) * mval;
        tile[tt * 1032 + c] = f2bf(conv);
        sum += conv; ssq += conv * conv;
    }
    psum[cc][tt] = sum; psq[cc][tt] = ssq;
    __syncthreads();
    if (tid < 16) {
        float s = 0.f, q2 = 0.f;
        for (int j = 0; j < 16; ++j) { s += psum[j][tid]; q2 += psq[j][tid]; }
        float mu = s * (1.f / 1024.f);
        float var = q2 * (1.f / 1024.f) - mu * mu;
        smu[tid] = mu;
        srs[tid] = rsqrtf(var + LN_EPS);
    }
    __syncthreads();

    int c4 = tid * 4;
    float g0 = g[c4], g1 = g[c4 + 1], g2 = g[c4 + 2], g3 = g[c4 + 3];
    float e0 = be[c4], e1 = be[c4 + 1], e2 = be[c4 + 2], e3 = be[c4 + 3];
    for (int r = 0; r < 16; ++r) {
        ushort4 tv = *reinterpret_cast<const ushort4*>(&tile[r * 1032 + c4]);
        float mu = smu[r], rs = srs[r];
        ushort4 o;
        o.x = f2bf((bf2f(tv.x) - mu) * rs * g0 + e0);
        o.y = f2bf((bf2f(tv.y) - mu) * rs * g1 + e1);
        o.z = f2bf((bf2f(tv.z) - mu) * rs * g2 + e2);
        o.w = f2bf((bf2f(tv.w) - mu) * rs * g3 + e3);
        *reinterpret_cast<ushort4*>(dst + (size_t)(b * NT + t0 + r) * NC + c4) = o;
    }
}

// ---------------------------------------------------------------------------
// q/k/v projections, LDS-staged 2-phase double-buffered (m97/T3-min structure).
// grid (24, 8, 3), block 256 (4 waves, 2x2, 64x64/wave).
__global__ __launch_bounds__(256) void gemm_qkv_kernel(
    const unsigned short* __restrict__ wqb, const unsigned short* __restrict__ wkb,
    const unsigned short* __restrict__ wvb,
    const unsigned short* __restrict__ xn, const unsigned short* __restrict__ yn,
    const unsigned short* __restrict__ zn,
    const float* __restrict__ bq, const float* __restrict__ bk, const float* __restrict__ bv,
    unsigned short* __restrict__ qo, unsigned short* __restrict__ ko,
    unsigned short* __restrict__ vt)
{
    __shared__ __align__(16) unsigned short lX[2][128 * BK];  // X tile (bt rows)
    __shared__ __align__(16) unsigned short lW[2][128 * BK];  // W tile (o rows)

    int which = blockIdx.z;
    const unsigned short* W = (which == 0) ? wqb : (which == 1) ? wkb : wvb;
    const unsigned short* X = (which == 0) ? xn : (which == 1) ? yn : zn;
    const float* bias = (which == 0) ? bq : (which == 1) ? bk : bv;

    int tid = threadIdx.x;
    int lane = tid & 63, w = tid >> 6;
    int nb = blockIdx.x * 128;   // bt tile base
    int ob = blockIdx.y * 128;   // out-channel tile base

    int srow = w * 16 + (lane >> 2);
    const unsigned short* gX = X + (size_t)(nb + srow) * NC + (lane & 3) * 8;
    const unsigned short* gW = W + (size_t)(ob + srow) * NC + (lane & 3) * 8;
    unsigned short* lX0 = &lX[0][0] + w * 16 * BK;
    unsigned short* lW0 = &lW[0][0] + w * 16 * BK;

#define QKV_STAGE(buf, k0) do {                                       \
    gload16(gX + (k0),           lX0 + (buf) * 128 * BK);             \
    gload16(gX + (k0) + 64 * NC, lX0 + (buf) * 128 * BK + 64 * BK);   \
    gload16(gW + (k0),           lW0 + (buf) * 128 * BK);             \
    gload16(gW + (k0) + 64 * NC, lW0 + (buf) * 128 * BK + 64 * BK);   \
} while (0)

    int r0 = lane & 15, kg = lane >> 4;
    const unsigned short* fW = &lW[0][0] + ((w & 1)  * 64 + r0) * BK + kg * 8;
    const unsigned short* fX = &lX[0][0] + ((w >> 1) * 64 + r0) * BK + kg * 8;

    f32x4 acc[4][4];
    #pragma unroll
    for (int i = 0; i < 4; ++i)
        #pragma unroll
        for (int j = 0; j < 4; ++j) acc[i][j] = (f32x4){0.f, 0.f, 0.f, 0.f};

#define QKV_COMPUTE(buf) do {                                                  \
    bf16x8 a_[4], b_[4];                                                       \
    _Pragma("unroll") for (int i = 0; i < 4; ++i)                              \
        a_[i] = ldbf8(fW + (buf) * 128 * BK + i * 16 * BK);                    \
    _Pragma("unroll") for (int i = 0; i < 4; ++i)                              \
        b_[i] = ldbf8(fX + (buf) * 128 * BK + i * 16 * BK);                    \
    _Pragma("unroll") for (int mf = 0; mf < 4; ++mf)                           \
        _Pragma("unroll") for (int nf = 0; nf < 4; ++nf)                       \
            acc[mf][nf] = mfma16(a_[mf], b_[nf], acc[mf][nf]);                 \
} while (0)

    QKV_STAGE(0, 0);
    #pragma unroll 1
    for (int k0 = 0; k0 < NC - 2 * BK; k0 += 2 * BK) {
        QKV_STAGE(1, k0 + BK);
        WAITV(4); BAR();
        QKV_COMPUTE(0);
        BAR();
        QKV_STAGE(0, k0 + 2 * BK);
        WAITV(4); BAR();
        QKV_COMPUTE(1);
        BAR();
    }
    QKV_STAGE(1, NC - BK);
    WAITV(4); BAR();
    QKV_COMPUTE(0);
    WAITV(0); BAR();
    QKV_COMPUTE(1);

    if (which < 2) {
        unsigned short* OUT = (which == 0) ? qo : ko;
        #pragma unroll
        for (int mf = 0; mf < 4; ++mf) {
            int o0 = ob + (w & 1) * 64 + mf * 16 + kg * 4;
            float4 bz = *reinterpret_cast<const float4*>(bias + o0);
            #pragma unroll
            for (int nf = 0; nf < 4; ++nf) {
                int n = nb + (w >> 1) * 64 + nf * 16 + r0;
                ushort4 st;
                st.x = f2bf(acc[mf][nf][0] + bz.x);
                st.y = f2bf(acc[mf][nf][1] + bz.y);
                st.z = f2bf(acc[mf][nf][2] + bz.z);
                st.w = f2bf(acc[mf][nf][3] + bz.w);
                *reinterpret_cast<ushort4*>(OUT + (size_t)n * NC + o0) = st;
            }
        }
    } else {
        #pragma unroll
        for (int mf = 0; mf < 4; ++mf) {
            int o0 = ob + (w & 1) * 64 + mf * 16 + kg * 4;
            #pragma unroll
            for (int nf = 0; nf < 4; ++nf) {
                int n = nb + (w >> 1) * 64 + nf * 16 + r0;
                #pragma unroll
                for (int r = 0; r < 4; ++r)
                    vt[(size_t)(o0 + r) * NBT + n] = f2bf(acc[mf][nf][r] + bias[o0 + r]);
            }
        }
    }
#undef QKV_STAGE
#undef QKV_COMPUTE
}

// ---------------------------------------------------------------------------
// Flash attention with block-level K-split: grid (NT/32, NB*NH), block 256.
// One block per 32-q tile; its 4 waves each cover a quarter of the K tiles
// (flash-decoding style), partial (m,l,O) merged through LDS by wave 0.
// Softmax in exp2 domain (scale folded with log2 e).
__global__ __launch_bounds__(256) void attn_kernel(
    const unsigned short* __restrict__ q, const unsigned short* __restrict__ kk,
    const unsigned short* __restrict__ vt, const int* __restrict__ mask,
    unsigned short* __restrict__ oatt)
{
    __shared__ float oL[3][64][33];   // +33 pad: (lane+r)&31 -> 2-way max (free)
    __shared__ float mL[3][64], lL[3][64];

    int lane = threadIdx.x & 63;
    int w = threadIdx.x >> 6;
    int b = blockIdx.y >> 4, h = blockIdx.y & 15;
    int q0 = blockIdx.x * 32;
    int ql = lane & 31;          // q column this lane owns
    int hi = lane >> 5;          // half-wave (k/d sub-slice)

    const int* mrow = mask + b * NT;
    int valid = 0;
    #pragma unroll
    for (int i = 0; i < NT / 64; ++i)
        valid += __popcll(__ballot(mrow[lane + 64 * i] != 0));
    if (q0 >= valid) return;     // masked q rows: oatt never observed downstream
    int ntiles = (valid + 31) >> 5;

    // this wave's K-chunk [tb, te)
    int per = ntiles >> 2, rem = ntiles & 3;
    int tb = w * per + (w < rem ? w : rem);
    int te = tb + per + (w < rem ? 1 : 0);

    const unsigned short* qp = q + (size_t)(b * NT + q0 + ql) * NC + h * ND + hi * 8;
    bf16x8 qf[4];
    #pragma unroll
    for (int dd = 0; dd < 4; ++dd) qf[dd] = ldbf8(qp + dd * 16);

    const f32x16 z16 = {0.f,0.f,0.f,0.f, 0.f,0.f,0.f,0.f, 0.f,0.f,0.f,0.f, 0.f,0.f,0.f,0.f};
    f32x16 o0 = z16, o1 = z16;   // O^T: q = ql, d = blk*32 + (r&3)+8*(r>>2)+4*hi
    float m = -1e30f, l = 0.f;

    const unsigned short* kbase = kk + (size_t)(b * NT) * NC + h * ND + hi * 8;
    const unsigned short* vbase = vt + (size_t)(h * ND) * NBT + b * NT + hi * 8;

    bf16x8 kf[4];
    if (tb < te) {
        #pragma unroll
        for (int dd = 0; dd < 4; ++dd)
            kf[dd] = ldbf8(kbase + (size_t)(tb * 32 + ql) * NC + dd * 16);
    }

    for (int t = tb; t < te; ++t) {
        int kb = t * 32;
        // S^T = K Q^T : lane holds S[k-spread][q=ql], 16 regs
        f32x16 s = z16;
        #pragma unroll
        for (int dd = 0; dd < 4; ++dd) s = mfma32(kf[dd], qf[dd], s);

        if (t + 1 < te) {
            #pragma unroll
            for (int dd = 0; dd < 4; ++dd)
                kf[dd] = ldbf8(kbase + (size_t)(kb + 32 + ql) * NC + dd * 16);
        }
        bf16x8 vf[2][2];
        #pragma unroll
        for (int d0 = 0; d0 < 2; ++d0)
            #pragma unroll
            for (int ks = 0; ks < 2; ++ks)
                vf[d0][ks] = ldbf8(vbase + (size_t)(d0 * 32 + ql) * NBT + kb + ks * 16);

        bool tail = (kb + 32 > valid);
        float pmax = -1e30f;
        #pragma unroll
        for (int r = 0; r < 16; ++r) {
            float sv = s[r] * QS2;
            if (tail) {
                int kg = kb + (r & 3) + 8 * (r >> 2) + 4 * hi;
                sv = (kg < valid) ? sv : -1e30f;
            }
            s[r] = sv;
            pmax = fmaxf(pmax, sv);
        }
        pmax = fmaxf(pmax, __shfl_xor(pmax, 32));

        if (__any(pmax > m)) {           // defer-max: skip rescale when possible
            float mn = fmaxf(m, pmax);
            float scale = exp2fast(m - mn);
            m = mn;
            l *= scale;
            o0 *= scale; o1 *= scale;
        }

        float rs = 0.f;
        unsigned cpk[8];
        #pragma unroll
        for (int i = 0; i < 8; ++i) {
            float pa = exp2fast(s[2 * i]     - m);
            float pb = exp2fast(s[2 * i + 1] - m);
            rs += pa + pb;
            cpk[i] = pkbf(pa, pb);
        }
        rs += __shfl_xor(rs, 32);
        l += rs;

        unsigned dpk[8];
        #pragma unroll
        for (int i = 0; i < 8; ++i) dpk[i] = __shfl_xor(cpk[i], 32);

        union { unsigned u[4]; bf16x8 v; } A0, A1;
        A0.u[0] = hi ? dpk[2] : cpk[0];
        A0.u[1] = hi ? dpk[3] : cpk[1];
        A0.u[2] = hi ? cpk[2] : dpk[0];
        A0.u[3] = hi ? cpk[3] : dpk[1];
        A1.u[0] = hi ? dpk[6] : cpk[4];
        A1.u[1] = hi ? dpk[7] : cpk[5];
        A1.u[2] = hi ? cpk[6] : dpk[4];
        A1.u[3] = hi ? cpk[7] : dpk[5];

        o0 = mfma32(vf[0][0], A0.v, o0);
        o0 = mfma32(vf[0][1], A1.v, o0);
        o1 = mfma32(vf[1][0], A0.v, o1);
        o1 = mfma32(vf[1][1], A1.v, o1);
    }

    // merge the 4 partial flash states: waves 1..3 publish, wave 0 reduces
    if (w > 0) {
        int wi = w - 1;
        #pragma unroll
        for (int r = 0; r < 16; ++r) {
            oL[wi][lane][r]      = o0[r];
            oL[wi][lane][16 + r] = o1[r];
        }
        mL[wi][lane] = m;
        lL[wi][lane] = l;
    }
    __syncthreads();
    if (w > 0) return;

    float M = m;
    float mw[3], lw[3];
    #pragma unroll
    for (int j = 0; j < 3; ++j) {
        mw[j] = mL[j][lane];
        lw[j] = lL[j][lane];
        M = fmaxf(M, mw[j]);
    }
    float s0 = exp2fast(m - M);
    float L = l * s0;
    o0 *= s0; o1 *= s0;
    #pragma unroll
    for (int j = 0; j < 3; ++j) {
        float sj = exp2fast(mw[j] - M);
        L += lw[j] * sj;
        #pragma unroll
        for (int r = 0; r < 16; ++r) {
            o0[r] += sj * oL[j][lane][r];
            o1[r] += sj * oL[j][lane][16 + r];
        }
    }

    float inv = (L > 0.f) ? (1.f / L) : 0.f;
    unsigned short* ob = oatt + (size_t)(b * NT + q0 + ql) * NC + h * ND;
    #pragma unroll
    for (int g = 0; g < 4; ++g) {
        ushort4 s0v, s1v;
        s0v.x = f2bf(o0[4 * g + 0] * inv); s0v.y = f2bf(o0[4 * g + 1] * inv);
        s0v.z = f2bf(o0[4 * g + 2] * inv); s0v.w = f2bf(o0[4 * g + 3] * inv);
        s1v.x = f2bf(o1[4 * g + 0] * inv); s1v.y = f2bf(o1[4 * g + 1] * inv);
        s1v.z = f2bf(o1[4 * g + 2] * inv); s1v.w = f2bf(o1[4 * g + 3] * inv);
        *reinterpret_cast<ushort4*>(ob + g * 8 + 4 * hi)      = s0v;
        *reinterpret_cast<ushort4*>(ob + 32 + g * 8 + 4 * hi) = s1v;
    }
}

// ---------------------------------------------------------------------------
// Output projection, LDS-staged 2-phase; stores contiguous along T, fused mask.
// grid (24, 8), block 256.
__global__ __launch_bounds__(256) void gemm_out_kernel(
    const unsigned short* __restrict__ oatt, const unsigned short* __restrict__ wpb,
    const float* __restrict__ bp, const int* __restrict__ mask,
    float* __restrict__ out)
{
    __shared__ __align__(16) unsigned short lA[2][128 * BK];  // oatt tile (bt rows)
    __shared__ __align__(16) unsigned short lB[2][128 * BK];  // wp tile (o rows)

    int tid = threadIdx.x;
    int lane = tid & 63, w = tid >> 6;
    int mb  = blockIdx.x * 128;  // bt tile base
    int obb = blockIdx.y * 128;  // out-channel tile base

    int srow = w * 16 + (lane >> 2);
    const unsigned short* gA = oatt + (size_t)(mb + srow) * NC + (lane & 3) * 8;
    const unsigned short* gB = wpb + (size_t)(obb + srow) * NC + (lane & 3) * 8;
    unsigned short* lA0 = &lA[0][0] + w * 16 * BK;
    unsigned short* lB0 = &lB[0][0] + w * 16 * BK;

#define OUT_STAGE(buf, k0) do {                                       \
    gload16(gA + (k0),           lA0 + (buf) * 128 * BK);             \
    gload16(gA + (k0) + 64 * NC, lA0 + (buf) * 128 * BK + 64 * BK);   \
    gload16(gB + (k0),           lB0 + (buf) * 128 * BK);             \
    gload16(gB + (k0) + 64 * NC, lB0 + (buf) * 128 * BK + 64 * BK);   \
} while (0)

    int r0 = lane & 15, kg = lane >> 4;
    const unsigned short* fA = &lA[0][0] + ((w >> 1) * 64 + r0) * BK + kg * 8;
    const unsigned short* fB = &lB[0][0] + ((w & 1)  * 64 + r0) * BK + kg * 8;

    f32x4 acc[4][4];
    #pragma unroll
    for (int i = 0; i < 4; ++i)
        #pragma unroll
        for (int j = 0; j < 4; ++j) acc[i][j] = (f32x4){0.f, 0.f, 0.f, 0.f};

#define OUT_COMPUTE(buf) do {                                                  \
    bf16x8 a_[4], b_[4];                                                       \
    _Pragma("unroll") for (int i = 0; i < 4; ++i)                              \
        a_[i] = ldbf8(fA + (buf) * 128 * BK + i * 16 * BK);                    \
    _Pragma("unroll") for (int i = 0; i < 4; ++i)                              \
        b_[i] = ldbf8(fB + (buf) * 128 * BK + i * 16 * BK);                    \
    _Pragma("unroll") for (int mf = 0; mf < 4; ++mf)                           \
        _Pragma("unroll") for (int nf = 0; nf < 4; ++nf)                       \
            acc[mf][nf] = mfma16(a_[mf], b_[nf], acc[mf][nf]);                 \
} while (0)

    OUT_STAGE(0, 0);
    #pragma unroll 1
    for (int k0 = 0; k0 < NC - 2 * BK; k0 += 2 * BK) {
        OUT_STAGE(1, k0 + BK);
        WAITV(4); BAR();
        OUT_COMPUTE(0);
        BAR();
        OUT_STAGE(0, k0 + 2 * BK);
        WAITV(4); BAR();
        OUT_COMPUTE(1);
        BAR();
    }
    OUT_STAGE(1, NC - BK);
    WAITV(4); BAR();
    OUT_COMPUTE(0);
    WAITV(0); BAR();
    OUT_COMPUTE(1);

    int b_ = (int)(blockIdx.x >= 12);
    size_t obase = (size_t)b_ * NC * NT;
    #pragma unroll
    for (int mf = 0; mf < 4; ++mf) {
        int bt0 = mb + (w >> 1) * 64 + mf * 16 + kg * 4;
        int4 mv = *reinterpret_cast<const int4*>(mask + bt0);
        float m0 = mv.x ? 1.f : 0.f;
        float m1 = mv.y ? 1.f : 0.f;
        float m2 = mv.z ? 1.f : 0.f;
        float m3 = mv.w ? 1.f : 0.f;
        int t0 = bt0 - b_ * NT;
        #pragma unroll
        for (int nf = 0; nf < 4; ++nf) {
            int o = obb + (w & 1) * 64 + nf * 16 + r0;
            float bz = bp[o];
            f32x4 vv;
            vv[0] = (acc[mf][nf][0] + bz) * m0;
            vv[1] = (acc[mf][nf][1] + bz) * m1;
            vv[2] = (acc[mf][nf][2] + bz) * m2;
            vv[3] = (acc[mf][nf][3] + bz) * m3;
            *reinterpret_cast<f32x4*>(out + obase + (size_t)o * NT + t0) = vv;
        }
    }
#undef OUT_STAGE
#undef OUT_COMPUTE
}

// ---------------------------------------------------------------------------
__global__ __launch_bounds__(256) void maskout_kernel(const int* __restrict__ mask,
                                                      float* __restrict__ out)
{
    int i = blockIdx.x * 256 + threadIdx.x;
    if (i < NBT) out[(size_t)NB * NC * NT + i] = (mask[i] != 0) ? 1.f : 0.f;
}

// ---------------------------------------------------------------------------
extern "C" void kernel_launch(void* const* d_in, const int* in_sizes, int n_in,
                              void* d_out, int out_size, void* d_ws, size_t ws_size,
                              hipStream_t stream)
{
    const float* x    = (const float*)d_in[0];
    const float* y    = (const float*)d_in[1];
    const float* z    = (const float*)d_in[2];
    const int*   mask = (const int*)d_in[3];
    const float* qw   = (const float*)d_in[4];
    const float* kw   = (const float*)d_in[5];
    const float* vw   = (const float*)d_in[6];
    const float* qg   = (const float*)d_in[7];
    const float* qb   = (const float*)d_in[8];
    const float* kgm  = (const float*)d_in[9];
    const float* kbt  = (const float*)d_in[10];
    const float* vg   = (const float*)d_in[11];
    const float* vb   = (const float*)d_in[12];
    const float* wq   = (const float*)d_in[13];
    const float* bq   = (const float*)d_in[14];
    const float* wk   = (const float*)d_in[15];
    const float* bk   = (const float*)d_in[16];
    const float* wv   = (const float*)d_in[17];
    const float* bv   = (const float*)d_in[18];
    const float* wp   = (const float*)d_in[19];
    const float* bp   = (const float*)d_in[20];

    unsigned short* xn  = (unsigned short*)d_ws;
    unsigned short* yn  = xn + (size_t)NBT * NC;
    unsigned short* zn  = yn + (size_t)NBT * NC;
    unsigned short* qo  = zn + (size_t)NBT * NC;
    unsigned short* ko  = qo + (size_t)NBT * NC;
    unsigned short* vt  = ko + (size_t)NBT * NC;
    unsigned short* wqb = vt + (size_t)NBT * NC;
    unsigned short* wkb = wqb + (size_t)NC * NC;
    unsigned short* wvb = wkb + (size_t)NC * NC;
    unsigned short* wpb = wvb + (size_t)NC * NC;
    unsigned short* oatt = xn;  // xn dead after gemm_qkv; reuse for attention out

    float* out = (float*)d_out;

    wcvt_kernel<<<dim3(1024, 4), 256, 0, stream>>>(wq, wk, wv, wp, wqb, wkb, wvb, wpb);
    convln_kernel<<<dim3(NT / 16, NB, 3), 256, 0, stream>>>(
        x, y, z, qw, kw, vw, qg, qb, kgm, kbt, vg, vb, mask, xn, yn, zn);
    gemm_qkv_kernel<<<dim3(NBT / 128, NC / 128, 3), 256, 0, stream>>>(
        wqb, wkb, wvb, xn, yn, zn, bq, bk, bv, qo, ko, vt);
    attn_kernel<<<dim3(NT / 32, NB * NH), 256, 0, stream>>>(qo, ko, vt, mask, oatt);
    gemm_out_kernel<<<dim3(NBT / 128, NC / 128), 256, 0, stream>>>(oatt, wpb, bp, mask, out);
    maskout_kernel<<<dim3(NBT / 256), 256, 0, stream>>>(mask, out);
}